// Round 10
// baseline (562.216 us; speedup 1.0000x reference)
//
#include <hip/hip_runtime.h>
#include <hip/hip_bf16.h>
#include <stdint.h>

// ---------------------------------------------------------------------------
// TDBU caption step, bf16-MFMA everywhere, K-cat fused chains.
//   cvt_all: branch-dispatched fp32->bf16 packing (NO dynamic-index arrays)
//   td = tanh([step|tf|h2p] @ [Wtd3|Wtd2|Wtd1]^T)   (one K=960 GEMM)
//   td2 = relu(td@W_td^T); GRU1; hb; attn (512-thr, 8 waves);
//   lang = tanh([att|h1] @ [Wl1|Wl2]^T) (K=640); lang2 = relu; GRU2.
// NOTE: __exp2f does NOT exist on this toolchain (collides with glibc math.h);
// use __builtin_amdgcn_exp2f (v_exp_f32, computes 2^x) instead.
// ---------------------------------------------------------------------------

typedef __attribute__((ext_vector_type(8))) short short8;
typedef __attribute__((ext_vector_type(4))) float f32x4;

#define DEV static __device__ __forceinline__

DEV float rcp_f(float x) { return __builtin_amdgcn_rcpf(x); }
DEV float exp2_f(float x) { return __builtin_amdgcn_exp2f(x); }
// tanh via sigmoid identity: no NaN at either extreme, ~5 VALU ops.
DEV float tanh2(float x) {
  const float t = exp2_f(-2.885390082f * x);    // e^{-2x}
  return __builtin_fmaf(2.0f, rcp_f(1.0f + t), -1.0f);
}
DEV float sigm2(float x) { return rcp_f(1.0f + exp2_f(-1.442695041f * x)); }
DEV float exp_f(float x) { return exp2_f(1.442695041f * x); }
DEV unsigned short f2bf(float x) {
  unsigned u = __float_as_uint(x);
  u += 0x7fffu + ((u >> 16) & 1u);
  return (unsigned short)(u >> 16);
}
DEV float bf2f(unsigned short s) { return __uint_as_float(((unsigned)s) << 16); }
DEV unsigned pk2(float a, float b) {
  return (unsigned)f2bf(a) | ((unsigned)f2bf(b) << 16);
}

// ---------------- cvt: fp32 -> bf16 pack, all params compile-time -----------
template<int K, int Kp, int LD, int C0>
DEV void cvt_job(const float* __restrict__ src, unsigned short* __restrict__ dst,
                 int q) {
  constexpr int Q = Kp / 4;
  const int r = q / Q;
  const int c = (q - r * Q) * 4;
  union { uint2 u; unsigned short s[4]; } o;
  if (K == Kp || c < K) {
    const float4 v = *(const float4*)&src[(size_t)r * K + c];
    o.s[0] = f2bf(v.x); o.s[1] = f2bf(v.y); o.s[2] = f2bf(v.z); o.s[3] = f2bf(v.w);
  } else {
    o.u.x = 0u; o.u.y = 0u;
  }
  *(uint2*)&dst[(size_t)r * LD + C0 + c] = o.u;
}

struct CvtArgs {
  const float *step, *tf, *h2p, *h1p, *wtd3, *wtd2, *wtd1, *wtd, *wfeat,
              *whidd, *wl1, *wl2, *wl, *g1wih, *g1whh, *g2wih, *g2whh;
  unsigned short *tdcatA, *h1pb, *tdcatW, *wtdb, *wfeatb, *whiddb,
                 *langcatW, *wlb, *g1wihb, *g1whhb, *g2wihb, *g2whhb;
};

// block ranges: each block = 256 threads x 4 elems
__global__ __launch_bounds__(256) void cvt_all(CvtArgs a) {
  const int bid = (int)blockIdx.x, tid = (int)threadIdx.x;
  if      (bid <  320) cvt_job<300, 320, 960,   0>(a.step,  a.tdcatA,   bid         * 256 + tid);
  else if (bid <  448) cvt_job<128, 128, 960, 320>(a.tf,    a.tdcatA,   (bid -  320) * 256 + tid);
  else if (bid <  960) cvt_job<512, 512, 960, 448>(a.h2p,   a.tdcatA,   (bid -  448) * 256 + tid);
  else if (bid < 1472) cvt_job<512, 512, 512,   0>(a.h1p,   a.h1pb,     (bid -  960) * 256 + tid);
  else if (bid < 1512) cvt_job<300, 320, 960,   0>(a.wtd3,  a.tdcatW,   (bid - 1472) * 256 + tid);
  else if (bid < 1528) cvt_job<128, 128, 960, 320>(a.wtd2,  a.tdcatW,   (bid - 1512) * 256 + tid);
  else if (bid < 1592) cvt_job<512, 512, 960, 448>(a.wtd1,  a.tdcatW,   (bid - 1528) * 256 + tid);
  else if (bid < 1608) cvt_job<128, 128, 128,   0>(a.wtd,   a.wtdb,     (bid - 1592) * 256 + tid);
  else if (bid < 1672) cvt_job<128, 128, 128,   0>(a.wfeat, a.wfeatb,   (bid - 1608) * 256 + tid);
  else if (bid < 1928) cvt_job<512, 512, 512,   0>(a.whidd, a.whiddb,   (bid - 1672) * 256 + tid);
  else if (bid < 1944) cvt_job<128, 128, 640,   0>(a.wl1,   a.langcatW, (bid - 1928) * 256 + tid);
  else if (bid < 2008) cvt_job<512, 512, 640, 128>(a.wl2,   a.langcatW, (bid - 1944) * 256 + tid);
  else if (bid < 2024) cvt_job<128, 128, 128,   0>(a.wl,    a.wlb,      (bid - 2008) * 256 + tid);
  else if (bid < 2216) cvt_job<128, 128, 128,   0>(a.g1wih, a.g1wihb,   (bid - 2024) * 256 + tid);
  else if (bid < 2984) cvt_job<512, 512, 512,   0>(a.g1whh, a.g1whhb,   (bid - 2216) * 256 + tid);
  else if (bid < 3176) cvt_job<128, 128, 128,   0>(a.g2wih, a.g2wihb,   (bid - 2984) * 256 + tid);
  else if (bid < 3944) cvt_job<512, 512, 512,   0>(a.g2whh, a.g2whhb,   (bid - 3176) * 256 + tid);
}

// ---------------- bf16 MFMA GEMM: C = A(M,K) @ W(N,K)^T --------------------
#define FACC 1
#define FRELU (1 << 2)
#define FTANH (2 << 2)
__global__ __launch_bounds__(256) void gemm_bf16(
    const unsigned short* __restrict__ A, const unsigned short* __restrict__ W,
    const float* __restrict__ bias, float* __restrict__ C,
    unsigned short* __restrict__ Cb, int M, int N, int K,
    int lda, int ldw, int flags)
{
  __shared__ unsigned short As[64][40];   // +8 pad
  __shared__ unsigned short Ws[64][40];
  const int bm = blockIdx.x * 64, bn = blockIdx.y * 64;
  const int tid = (int)threadIdx.x;
  const int w = tid >> 6, l = tid & 63, l15 = l & 15, lg = l >> 4;
  const int wr = w >> 1, wc = w & 1;
  const int srow = tid >> 2, sq = tid & 3;

  f32x4 acc[2][2] = {};

  for (int k0 = 0; k0 < K; k0 += 32) {
    const uint4 va = *(const uint4*)(A + (size_t)(bm + srow) * lda + k0 + sq * 8);
    const uint4 vw = *(const uint4*)(W + (size_t)(bn + srow) * ldw + k0 + sq * 8);
    __syncthreads();
    *(uint4*)&As[srow][sq * 8] = va;
    *(uint4*)&Ws[srow][sq * 8] = vw;
    __syncthreads();

    short8 af[2], bf[2];
#pragma unroll
    for (int mi = 0; mi < 2; ++mi) {
      const int ar = wr * 32 + mi * 16 + l15;
      union { short8 s8; uint2 u[2]; } f;
      f.u[0] = *(const uint2*)&As[ar][lg * 4];
      f.u[1] = *(const uint2*)&As[ar][16 + lg * 4];
      af[mi] = f.s8;
    }
#pragma unroll
    for (int ni = 0; ni < 2; ++ni) {
      const int br = wc * 32 + ni * 16 + l15;
      union { short8 s8; uint2 u[2]; } f;
      f.u[0] = *(const uint2*)&Ws[br][lg * 4];
      f.u[1] = *(const uint2*)&Ws[br][16 + lg * 4];
      bf[ni] = f.s8;
    }
#pragma unroll
    for (int mi = 0; mi < 2; ++mi)
#pragma unroll
      for (int ni = 0; ni < 2; ++ni)
        acc[mi][ni] = __builtin_amdgcn_mfma_f32_16x16x32_bf16(
            af[mi], bf[ni], acc[mi][ni], 0, 0, 0);
  }

  const int act = flags >> 2;
#pragma unroll
  for (int mi = 0; mi < 2; ++mi)
#pragma unroll
    for (int ni = 0; ni < 2; ++ni)
#pragma unroll
      for (int r = 0; r < 4; ++r) {
        const int m = bm + wr * 32 + mi * 16 + lg * 4 + r;
        const int n = bn + wc * 32 + ni * 16 + l15;
        float v = acc[mi][ni][r];
        if (bias) v += bias[n];
        if (flags & FACC) v += C[(size_t)m * N + n];
        if (act == 1) v = fmaxf(v, 0.0f);
        else if (act == 2) v = tanh2(v);
        if (C) C[(size_t)m * N + n] = v;
        if (Cb) Cb[(size_t)m * N + n] = f2bf(v);
      }
}

// ---------------- GRU combine (bf16 gates, fp32 h) --------------------------
__global__ __launch_bounds__(256) void gru_combine(
    const unsigned short* __restrict__ gi, const unsigned short* __restrict__ gh,
    const float* __restrict__ hprev, float* __restrict__ hnew,
    unsigned short* __restrict__ hnewb, int ldhb)
{
  const int i4 = blockIdx.x * 256 + (int)threadIdx.x;   // over 131072
  const int b = i4 >> 7, j4 = (i4 & 127) * 4;
  const unsigned short* gib = gi + (size_t)b * 1536 + j4;
  const unsigned short* ghb = gh + (size_t)b * 1536 + j4;
  union { uint2 u; unsigned short s[4]; } gr, gz, gn, hr, hz, hn;
  gr.u = *(const uint2*)(gib);        hr.u = *(const uint2*)(ghb);
  gz.u = *(const uint2*)(gib + 512);  hz.u = *(const uint2*)(ghb + 512);
  gn.u = *(const uint2*)(gib + 1024); hn.u = *(const uint2*)(ghb + 1024);
  const float4 hp = *(const float4*)&hprev[(size_t)b * 512 + j4];
  const float hpv[4] = {hp.x, hp.y, hp.z, hp.w};
  float o[4];
  union { uint2 u; unsigned short s[4]; } ob;
#pragma unroll
  for (int k = 0; k < 4; ++k) {
    const float r = sigm2(bf2f(gr.s[k]) + bf2f(hr.s[k]));
    const float z = sigm2(bf2f(gz.s[k]) + bf2f(hz.s[k]));
    const float n = tanh2(bf2f(gn.s[k]) + r * bf2f(hn.s[k]));
    o[k] = (1.0f - z) * n + z * hpv[k];
    ob.s[k] = f2bf(o[k]);
  }
  float4 ov; ov.x = o[0]; ov.y = o[1]; ov.z = o[2]; ov.w = o[3];
  *(float4*)&hnew[(size_t)b * 512 + j4] = ov;
  if (hnewb) *(uint2*)&hnewb[(size_t)b * ldhb + j4] = ob.u;
}

// ---------------- fused attention: 512 threads, 8 waves x 32 rows ----------
__global__ __launch_bounds__(512, 6) void attn_kernel(
    const float* __restrict__ obj, const unsigned short* __restrict__ wf,
    const float* __restrict__ hb, const float* __restrict__ watt,
    float* __restrict__ masks_out, unsigned short* __restrict__ attb)
{
  __shared__ __align__(16) float scores[256];
  __shared__ __align__(16) float smasks[256];
  __shared__ float attw[8][128];
  __shared__ float hbs[512];
  __shared__ float wats[512];

  const int b = (int)blockIdx.x;
  const int tid = (int)threadIdx.x;
  const int w = tid >> 6, l = tid & 63;
  const int l15 = l & 15, lg = l >> 4;

  const float* objb = obj + (size_t)b * 32768;
  const float* hbb = hb + (size_t)b * 512;
  hbs[tid] = hbb[tid];
  wats[tid] = watt[tid];

  // this wave's 32 obj rows as bf16 A fragments (registers)
  short8 afrag[2][4];
#pragma unroll
  for (int mt = 0; mt < 2; ++mt) {
    const float* prow = objb + (size_t)(w * 32 + mt * 16 + l15) * 128;
#pragma unroll
    for (int kt = 0; kt < 4; ++kt) {
      union { short8 s8; unsigned u[4]; } fr;
#pragma unroll
      for (int half = 0; half < 2; ++half) {
        const float4 v = *(const float4*)&prow[kt * 32 + half * 16 + lg * 4];
        fr.u[half * 2 + 0] = pk2(v.x, v.y);
        fr.u[half * 2 + 1] = pk2(v.z, v.w);
      }
      afrag[mt][kt] = fr.s8;
    }
  }
  __syncthreads();

  // scores: S = obj@W_feat.T fused with sum_h watt*tanh(S+hb)
  float ps[2][4] = {};
  for (int nc = 0; nc < 32; ++nc) {
    const int hh = nc * 16 + l15;
    const unsigned short* wrow = wf + (size_t)hh * 128;
    f32x4 a0 = {0.f, 0.f, 0.f, 0.f}, a1 = {0.f, 0.f, 0.f, 0.f};
#pragma unroll
    for (int kk = 0; kk < 2; ++kk) {
      short8 b0, b1;
      {
        union { short8 s8; uint2 u[2]; } f;
        f.u[0] = *(const uint2*)&wrow[(kk * 2) * 32 + lg * 4];
        f.u[1] = *(const uint2*)&wrow[(kk * 2) * 32 + 16 + lg * 4];
        b0 = f.s8;
      }
      {
        union { short8 s8; uint2 u[2]; } f;
        f.u[0] = *(const uint2*)&wrow[(kk * 2 + 1) * 32 + lg * 4];
        f.u[1] = *(const uint2*)&wrow[(kk * 2 + 1) * 32 + 16 + lg * 4];
        b1 = f.s8;
      }
      a0 = __builtin_amdgcn_mfma_f32_16x16x32_bf16(afrag[0][kk * 2],     b0, a0, 0, 0, 0);
      a0 = __builtin_amdgcn_mfma_f32_16x16x32_bf16(afrag[0][kk * 2 + 1], b1, a0, 0, 0, 0);
      a1 = __builtin_amdgcn_mfma_f32_16x16x32_bf16(afrag[1][kk * 2],     b0, a1, 0, 0, 0);
      a1 = __builtin_amdgcn_mfma_f32_16x16x32_bf16(afrag[1][kk * 2 + 1], b1, a1, 0, 0, 0);
    }
    const float hbv = hbs[hh];
    const float wav = wats[hh];
#pragma unroll
    for (int r = 0; r < 4; ++r) {
      ps[0][r] = __builtin_fmaf(wav, tanh2(a0[r] + hbv), ps[0][r]);
      ps[1][r] = __builtin_fmaf(wav, tanh2(a1[r] + hbv), ps[1][r]);
    }
  }

  // reduce partial scores over the 16 col-lanes -> scores[p]
#pragma unroll
  for (int mt = 0; mt < 2; ++mt)
#pragma unroll
    for (int r = 0; r < 4; ++r) {
      float v = ps[mt][r];
      v += __shfl_xor(v, 1);
      v += __shfl_xor(v, 2);
      v += __shfl_xor(v, 4);
      v += __shfl_xor(v, 8);
      if (l15 == 0) scores[w * 32 + mt * 16 + lg * 4 + r] = v;
    }
  __syncthreads();

  // softmax over 256 (wave 0 only; lane l owns p = 4l..4l+3)
  if (w == 0) {
    const float4 sv = *(const float4*)&scores[l * 4];
    float mx = fmaxf(fmaxf(sv.x, sv.y), fmaxf(sv.z, sv.w));
#pragma unroll
    for (int off = 32; off > 0; off >>= 1) mx = fmaxf(mx, __shfl_xor(mx, off));
    const float e0 = exp_f(sv.x - mx), e1 = exp_f(sv.y - mx);
    const float e2 = exp_f(sv.z - mx), e3 = exp_f(sv.w - mx);
    float sm = (e0 + e1) + (e2 + e3);
#pragma unroll
    for (int off = 32; off > 0; off >>= 1) sm += __shfl_xor(sm, off);
    const float rt = rcp_f(sm);
    float4 mk; mk.x = e0 * rt; mk.y = e1 * rt; mk.z = e2 * rt; mk.w = e3 * rt;
    *(float4*)&masks_out[(size_t)b * 256 + l * 4] = mk;
    *(float4*)&smasks[l * 4] = mk;
  }
  __syncthreads();

  // attended = sum_p mask[p]*obj[p][:], from register fragments
  float att_acc[8][4] = {};
#pragma unroll
  for (int mt = 0; mt < 2; ++mt) {
    const float mk = smasks[w * 32 + mt * 16 + l15];
#pragma unroll
    for (int kt = 0; kt < 4; ++kt)
#pragma unroll
      for (int half = 0; half < 2; ++half)
#pragma unroll
        for (int j = 0; j < 4; ++j)
          att_acc[kt * 2 + half][j] =
              __builtin_fmaf(mk, bf2f((unsigned short)afrag[mt][kt][half * 4 + j]),
                             att_acc[kt * 2 + half][j]);
  }
#pragma unroll
  for (int slot = 0; slot < 8; ++slot)
#pragma unroll
    for (int j = 0; j < 4; ++j) {
      float v = att_acc[slot][j];
      v += __shfl_xor(v, 1);
      v += __shfl_xor(v, 2);
      v += __shfl_xor(v, 4);
      v += __shfl_xor(v, 8);
      if (l15 == 0) {
        const int kt = slot >> 1, half = slot & 1;
        attw[w][kt * 32 + half * 16 + lg * 4 + j] = v;
      }
    }
  __syncthreads();
  if (tid < 128) {
    float s = 0.f;
#pragma unroll
    for (int q = 0; q < 8; ++q) s += attw[q][tid];
    attb[(size_t)b * 640 + tid] = f2bf(s);   // langcatA col 0, stride 640
  }
}

// ---------------------------------------------------------------------------
extern "C" void kernel_launch(void* const* d_in, const int* in_sizes, int n_in,
                              void* d_out, int out_size, void* d_ws, size_t ws_size,
                              hipStream_t stream) {
  (void)in_sizes; (void)n_in; (void)out_size; (void)ws_size;
  const float* step   = (const float*)d_in[0];
  const float* tf     = (const float*)d_in[1];
  const float* obj    = (const float*)d_in[2];
  const float* h1prev = (const float*)d_in[3];
  const float* h2prev = (const float*)d_in[4];
  const float* W_td1  = (const float*)d_in[5];
  const float* W_td2  = (const float*)d_in[6];
  const float* W_td3  = (const float*)d_in[7];
  const float* W_td   = (const float*)d_in[8];
  const float* W_feat = (const float*)d_in[9];
  const float* W_hidd = (const float*)d_in[10];
  const float* W_att  = (const float*)d_in[11];
  const float* W_l1   = (const float*)d_in[12];
  const float* W_l2   = (const float*)d_in[13];
  const float* W_l    = (const float*)d_in[14];
  const float* g1Wih  = (const float*)d_in[15];
  const float* g1Whh  = (const float*)d_in[16];
  const float* g1bih  = (const float*)d_in[17];
  const float* g1bhh  = (const float*)d_in[18];
  const float* g2Wih  = (const float*)d_in[19];
  const float* g2Whh  = (const float*)d_in[20];
  const float* g2bih  = (const float*)d_in[21];
  const float* g2bhh  = (const float*)d_in[22];

  float* h1    = (float*)d_out;
  float* h2    = (float*)d_out + 524288;
  float* masks = (float*)d_out + 1048576;

  // ---- workspace (bf16 element offsets) ----
  unsigned short* wsb = (unsigned short*)d_ws;
  unsigned short* tdcatA   = wsb + 0;        // 1024x960 = 983040
  unsigned short* h1p_b    = wsb + 983040;   // 1024x512 = 524288
  unsigned short* tdcatW   = wsb + 1507328;  // 128x960  = 122880
  unsigned short* wtdb     = wsb + 1630208;  // 128x128  = 16384
  unsigned short* wfeatb   = wsb + 1646592;  // 512x128  = 65536
  unsigned short* whiddb   = wsb + 1712128;  // 512x512  = 262144
  unsigned short* langcatW = wsb + 1974272;  // 128x640  = 81920
  unsigned short* wlb      = wsb + 2056192;  // 128x128  = 16384
  unsigned short* g1wihb   = wsb + 2072576;  // 1536x128 = 196608
  unsigned short* g1whhb   = wsb + 2269184;  // 1536x512 = 786432
  unsigned short* g2wihb   = wsb + 3055616;  // 196608
  unsigned short* g2whhb   = wsb + 3252224;  // 786432
  unsigned short* tdb      = wsb + 4038656;  // 1024x128 = 131072
  unsigned short* td2b     = wsb + 4169728;  // 131072
  unsigned short* langcatA = wsb + 4300800;  // 1024x640 = 655360 ([att|h1])
  unsigned short* langb    = wsb + 4956160;  // 131072
  unsigned short* lang2b   = wsb + 5087232;  // 131072
  unsigned short* gi_b     = wsb + 5218304;  // 1024x1536 = 1572864
  unsigned short* gh_b     = wsb + 6791168;  // 1572864
  // fp32 hb scratch aliased on gh_b (disjoint lifetime: after GRU1 combine,
  // dead before GRU2 gh GEMM)
  float* scratchf = (float*)(wsb + 6791168); // 1024x512 f32

  const dim3 blk(256);

  // phase 0: conversions + cat packing
  CvtArgs a;
  a.step = step; a.tf = tf; a.h2p = h2prev; a.h1p = h1prev;
  a.wtd3 = W_td3; a.wtd2 = W_td2; a.wtd1 = W_td1; a.wtd = W_td;
  a.wfeat = W_feat; a.whidd = W_hidd; a.wl1 = W_l1; a.wl2 = W_l2; a.wl = W_l;
  a.g1wih = g1Wih; a.g1whh = g1Whh; a.g2wih = g2Wih; a.g2whh = g2Whh;
  a.tdcatA = tdcatA; a.h1pb = h1p_b; a.tdcatW = tdcatW; a.wtdb = wtdb;
  a.wfeatb = wfeatb; a.whiddb = whiddb; a.langcatW = langcatW; a.wlb = wlb;
  a.g1wihb = g1wihb; a.g1whhb = g1whhb; a.g2wihb = g2wihb; a.g2whhb = g2whhb;
  cvt_all<<<dim3(3944), blk, 0, stream>>>(a);

  // phase 1: td chain (K-cat 960, tanh) then td2 (relu)
  gemm_bf16<<<dim3(16, 2), blk, 0, stream>>>(tdcatA, tdcatW, nullptr, nullptr, tdb,  1024, 128, 960, 960, 960, FTANH);
  gemm_bf16<<<dim3(16, 2), blk, 0, stream>>>(tdb,    wtdb,   nullptr, nullptr, td2b, 1024, 128, 128, 128, 128, FRELU);

  // phase 2: GRU1 (h1b lands in langcatA cols 128-639)
  gemm_bf16<<<dim3(16, 24), blk, 0, stream>>>(td2b,  g1wihb, g1bih, nullptr, gi_b, 1024, 1536, 128, 128, 128, 0);
  gemm_bf16<<<dim3(16, 24), blk, 0, stream>>>(h1p_b, g1whhb, g1bhh, nullptr, gh_b, 1024, 1536, 512, 512, 512, 0);
  gru_combine<<<dim3(512), blk, 0, stream>>>(gi_b, gh_b, h1prev, h1, langcatA + 128, 640);

  // phase 3: hb = h1 @ W_hidd.T (reads h1b from langcatA, lda=640)
  gemm_bf16<<<dim3(16, 8), blk, 0, stream>>>(langcatA + 128, whiddb, nullptr, scratchf, nullptr, 1024, 512, 512, 640, 512, 0);

  // phase 4: attention (masks -> d_out, attended bf16 -> langcatA col 0)
  attn_kernel<<<dim3(1024), dim3(512), 0, stream>>>(obj, wfeatb, scratchf, W_att, masks, langcatA);

  // phase 5: lang chain (K-cat 640, tanh) then lang2 (relu)
  gemm_bf16<<<dim3(16, 2), blk, 0, stream>>>(langcatA, langcatW, nullptr, nullptr, langb,  1024, 128, 640, 640, 640, FTANH);
  gemm_bf16<<<dim3(16, 2), blk, 0, stream>>>(langb,    wlb,      nullptr, nullptr, lang2b, 1024, 128, 128, 128, 128, FRELU);

  // phase 6: GRU2 (h2prev bf16 read from tdcatA cols 448-959, lda=960)
  gemm_bf16<<<dim3(16, 24), blk, 0, stream>>>(lang2b,       g2wihb, g2bih, nullptr, gi_b, 1024, 1536, 128, 128, 128, 0);
  gemm_bf16<<<dim3(16, 24), blk, 0, stream>>>(tdcatA + 448, g2whhb, g2bhh, nullptr, gh_b, 1024, 1536, 512, 960, 512, 0);
  gru_combine<<<dim3(512), blk, 0, stream>>>(gi_b, gh_b, h2prev, h2, nullptr, 0);
}